// Round 1
// baseline (268.163 us; speedup 1.0000x reference)
//
#include <hip/hip_runtime.h>
#include <stdint.h>

// Problem dims
#define TOKENS 8192      // 4*2048
#define IN_F   3072
#define PAD_F  4096
#define N_OUT  4096
#define K_DIM  4096

using i32x4 = __attribute__((ext_vector_type(4))) int;

// -------- workspace layout (bytes) --------
// q_act  int8 [8192][4096]  @ 0          (33554432)
// w_q    int8 [4096][4096]  @ 33554432   (16777216)
// ainv   f32  [8192]        @ 50331648   (32768)
// partial f32 [4096]        @ 50364416   (16384)
// wscale f32  [1]           @ 50380800
#define Q_OFF    0
#define WQ_OFF   33554432
#define AINV_OFF 50331648
#define PART_OFF 50364416
#define WSC_OFF  50380800

__device__ __forceinline__ void gload_lds16(const void* g, void* l) {
    __builtin_amdgcn_global_load_lds(
        (__attribute__((address_space(1))) void*)(void*)g,
        (__attribute__((address_space(3))) void*)l,
        16, 0, 0);
}

// ---------------- weight absmean: partial sums ----------------
__global__ __launch_bounds__(256) void k_wabs(const float* __restrict__ w,
                                              float* __restrict__ partial) {
    int tid = threadIdx.x;
    const float4* w4 = (const float4*)(w + (size_t)blockIdx.x * 4096);
    float s = 0.f;
#pragma unroll
    for (int i = 0; i < 4; ++i) {
        float4 v = w4[tid + i * 256];
        s += fabsf(v.x) + fabsf(v.y) + fabsf(v.z) + fabsf(v.w);
    }
#pragma unroll
    for (int o = 32; o > 0; o >>= 1) s += __shfl_xor(s, o);
    __shared__ float rb[4];
    if ((tid & 63) == 0) rb[tid >> 6] = s;
    __syncthreads();
    if (tid == 0) partial[blockIdx.x] = rb[0] + rb[1] + rb[2] + rb[3];
}

// ---------------- finalize weight scale ----------------
__global__ __launch_bounds__(256) void k_wscale(const float* __restrict__ partial,
                                                float* __restrict__ wsp) {
    int tid = threadIdx.x;
    float s = 0.f;
#pragma unroll
    for (int i = 0; i < 16; ++i) s += partial[tid + i * 256];
#pragma unroll
    for (int o = 32; o > 0; o >>= 1) s += __shfl_xor(s, o);
    __shared__ float rb[4];
    if ((tid & 63) == 0) rb[tid >> 6] = s;
    __syncthreads();
    if (tid == 0)
        wsp[0] = fmaxf((rb[0] + rb[1] + rb[2] + rb[3]) * (1.0f / 16777216.0f), 1e-5f);
}

// ---------------- ternary weight quant ----------------
__global__ __launch_bounds__(256) void k_wquant(const float* __restrict__ w,
                                                const float* __restrict__ wsp,
                                                unsigned int* __restrict__ wq) {
    int idx = blockIdx.x * 256 + threadIdx.x;   // float4 group index
    float ws = wsp[0];
    float4 v = ((const float4*)w)[idx];
    int a = (int)rintf(v.x / ws); a = max(-1, min(1, a));
    int b = (int)rintf(v.y / ws); b = max(-1, min(1, b));
    int c = (int)rintf(v.z / ws); c = max(-1, min(1, c));
    int d = (int)rintf(v.w / ws); d = max(-1, min(1, d));
    unsigned int p = (unsigned)(a & 255) | ((unsigned)(b & 255) << 8) |
                     ((unsigned)(c & 255) << 16) | ((unsigned)(d & 255) << 24);
    wq[idx] = p;
}

// ---------------- fused LayerNorm + pad + FWHT + int8 absmax quant ----------------
__global__ __launch_bounds__(256) void k_lnfwht(const float* __restrict__ x,
                                                const float* __restrict__ gamma,
                                                const float* __restrict__ beta,
                                                unsigned int* __restrict__ q,
                                                float* __restrict__ ainv) {
    __shared__ float s[PAD_F];
    __shared__ float rb[8];
    int tid = threadIdx.x;
    int t = blockIdx.x;
    const float* xr = x + (size_t)t * IN_F;

    float v[12];
    float sum = 0.f;
#pragma unroll
    for (int i = 0; i < 12; ++i) { v[i] = xr[tid + i * 256]; sum += v[i]; }
#pragma unroll
    for (int o = 32; o > 0; o >>= 1) sum += __shfl_xor(sum, o);
    if ((tid & 63) == 0) rb[tid >> 6] = sum;
    __syncthreads();
    float mu = (rb[0] + rb[1] + rb[2] + rb[3]) * (1.0f / 3072.0f);

    float s2 = 0.f;
#pragma unroll
    for (int i = 0; i < 12; ++i) { float d = v[i] - mu; s2 += d * d; }
#pragma unroll
    for (int o = 32; o > 0; o >>= 1) s2 += __shfl_xor(s2, o);
    if ((tid & 63) == 0) rb[4 + (tid >> 6)] = s2;
    __syncthreads();
    float var = (rb[4] + rb[5] + rb[6] + rb[7]) * (1.0f / 3072.0f);
    float rstd = 1.0f / sqrtf(var + 1e-6f);

#pragma unroll
    for (int i = 0; i < 12; ++i) {
        int idx = tid + i * 256;
        s[idx] = (v[i] - mu) * rstd * gamma[idx] + beta[idx];
    }
#pragma unroll
    for (int i = 0; i < 4; ++i) s[IN_F + tid + i * 256] = 0.f;
    __syncthreads();

    // FWHT, 12 stages (order of butterflies is irrelevant for Hadamard)
    for (int h = 1; h < PAD_F; h <<= 1) {
#pragma unroll
        for (int jj = 0; jj < 8; ++jj) {
            int j = tid + jj * 256;                       // 0..2047
            int i0 = ((j & ~(h - 1)) << 1) | (j & (h - 1));
            float a = s[i0], b = s[i0 + h];
            s[i0] = a + b;
            s[i0 + h] = a - b;
        }
        __syncthreads();
    }

    // absmax of fwht/64
    float mx = 0.f;
#pragma unroll
    for (int i = 0; i < 16; ++i) mx = fmaxf(mx, fabsf(s[tid + i * 256]));
#pragma unroll
    for (int o = 32; o > 0; o >>= 1) mx = fmaxf(mx, __shfl_xor(mx, o));
    if ((tid & 63) == 0) rb[tid >> 6] = mx;
    __syncthreads();
    float amraw = fmaxf(fmaxf(rb[0], rb[1]), fmaxf(rb[2], rb[3]));
    float amax = fmaxf(amraw * (1.0f / 64.0f), 1e-5f);
    float scale = 127.0f / amax;
    if (tid == 0) ainv[t] = amax * (1.0f / 127.0f);

    unsigned int* qr = q + (size_t)t * (PAD_F / 4);
#pragma unroll
    for (int i = 0; i < 4; ++i) {
        int g = tid + i * 256;                 // int8x4 group
        unsigned int p = 0;
#pragma unroll
        for (int e = 0; e < 4; ++e) {
            float xh = s[4 * g + e] * (1.0f / 64.0f);
            int qi = (int)rintf(xh * scale);
            qi = max(-128, min(127, qi));
            p |= (unsigned)(qi & 255) << (8 * e);
        }
        qr[g] = p;
    }
}

// ---------------- int8 MFMA GEMM: out[m][n] = (sum_k q[m][k]*t[n][k]) * wsc * ainv[m] ----------------
#define BM 128
#define BN 128
#define BK 64

__global__ __launch_bounds__(256) void k_gemm(const signed char* __restrict__ Aq,
                                              const signed char* __restrict__ Wq,
                                              const float* __restrict__ ainv,
                                              const float* __restrict__ wsp,
                                              float* __restrict__ out) {
    __shared__ signed char As[BM * BK];   // [128][64] row-major, linear
    __shared__ signed char Bs[BN * BK];
    int tid = threadIdx.x;
    int lane = tid & 63, wid = tid >> 6;
    int bm = blockIdx.y * BM, bn = blockIdx.x * BN;
    int wm = wid >> 1, wn = wid & 1;

    // staging: wave w covers 16 rows per issue; lane l -> row w*16 + l/4, byte (l%4)*16
    const signed char* gA0 = Aq + (size_t)(bm + wid * 16 + (lane >> 2)) * K_DIM + (lane & 3) * 16;
    const signed char* gB0 = Wq + (size_t)(bn + wid * 16 + (lane >> 2)) * K_DIM + (lane & 3) * 16;
    signed char* lA0 = &As[wid * 1024];
    signed char* lA1 = &As[(wid + 4) * 1024];
    signed char* lB0 = &Bs[wid * 1024];
    signed char* lB1 = &Bs[(wid + 4) * 1024];
    const size_t rowStride64 = (size_t)64 * K_DIM;

    i32x4 acc[4][4];
#pragma unroll
    for (int m = 0; m < 4; ++m)
#pragma unroll
        for (int n = 0; n < 4; ++n) acc[m][n] = (i32x4){0, 0, 0, 0};

    int lrow = lane & 15, kseg = lane >> 4;
    const i32x4* vA = (const i32x4*)As;
    const i32x4* vB = (const i32x4*)Bs;
    // A frag m: bytes [(wm*64 + m*16 + lrow)*64 + kseg*16 .. +16)
    int baseA = (wm * 64 + lrow) * 4 + kseg;
    int baseB = (wn * 64 + lrow) * 4 + kseg;

    for (int k0 = 0; k0 < K_DIM; k0 += BK) {
        __syncthreads();                 // previous compute done before overwrite
        gload_lds16(gA0 + k0, lA0);
        gload_lds16(gA0 + k0 + rowStride64, lA1);
        gload_lds16(gB0 + k0, lB0);
        gload_lds16(gB0 + k0 + rowStride64, lB1);
        __syncthreads();                 // staging complete (vmcnt drained at barrier)

        i32x4 af[4], bf[4];
#pragma unroll
        for (int m = 0; m < 4; ++m) af[m] = vA[baseA + m * 64];
#pragma unroll
        for (int n = 0; n < 4; ++n) bf[n] = vB[baseB + n * 64];
#pragma unroll
        for (int m = 0; m < 4; ++m)
#pragma unroll
            for (int n = 0; n < 4; ++n)
                acc[m][n] = __builtin_amdgcn_mfma_i32_16x16x64_i8(af[m], bf[n], acc[m][n], 0, 0, 0);
    }

    float wsc = wsp[0];
#pragma unroll
    for (int m = 0; m < 4; ++m) {
        int row0 = bm + wm * 64 + m * 16 + kseg * 4;
#pragma unroll
        for (int r = 0; r < 4; ++r) {
            int row = row0 + r;
            float sa = wsc * ainv[row];
#pragma unroll
            for (int n = 0; n < 4; ++n) {
                int col = bn + wn * 64 + n * 16 + lrow;
                out[(size_t)row * N_OUT + col] = (float)acc[m][n][r] * sa;
            }
        }
    }
}

extern "C" void kernel_launch(void* const* d_in, const int* in_sizes, int n_in,
                              void* d_out, int out_size, void* d_ws, size_t ws_size,
                              hipStream_t stream) {
    const float* x     = (const float*)d_in[0];
    const float* gamma = (const float*)d_in[1];
    const float* beta  = (const float*)d_in[2];
    const float* w     = (const float*)d_in[3];
    float* out = (float*)d_out;
    char* ws = (char*)d_ws;

    signed char* q   = (signed char*)(ws + Q_OFF);
    signed char* wq  = (signed char*)(ws + WQ_OFF);
    float* ainv      = (float*)(ws + AINV_OFF);
    float* partial   = (float*)(ws + PART_OFF);
    float* wsp       = (float*)(ws + WSC_OFF);

    k_wabs<<<dim3(4096), dim3(256), 0, stream>>>(w, partial);
    k_wscale<<<dim3(1), dim3(256), 0, stream>>>(partial, wsp);
    k_wquant<<<dim3(16384), dim3(256), 0, stream>>>(w, wsp, (unsigned int*)wq);
    k_lnfwht<<<dim3(TOKENS), dim3(256), 0, stream>>>(x, gamma, beta, (unsigned int*)q, ainv);
    k_gemm<<<dim3(N_OUT / BN, TOKENS / BM), dim3(256), 0, stream>>>(q, wq, ainv, wsp, out);
}

// Round 2
// 251.051 us; speedup vs baseline: 1.0682x; 1.0682x over previous
//
#include <hip/hip_runtime.h>
#include <stdint.h>

// Problem dims
#define TOKENS 8192      // 4*2048
#define IN_F   3072
#define PAD_F  4096
#define N_OUT  4096
#define K_DIM  4096

using i32x4 = __attribute__((ext_vector_type(4))) int;

// -------- workspace layout (bytes) --------
#define Q_OFF    0
#define WQ_OFF   33554432
#define AINV_OFF 50331648
#define PART_OFF 50364416
#define WSC_OFF  50380800

__device__ __forceinline__ void gload_lds16(const void* g, void* l) {
    __builtin_amdgcn_global_load_lds(
        (__attribute__((address_space(1))) void*)(void*)g,
        (__attribute__((address_space(3))) void*)l,
        16, 0, 0);
}

// ---------------- weight absmean: partial sums ----------------
__global__ __launch_bounds__(256) void k_wabs(const float* __restrict__ w,
                                              float* __restrict__ partial) {
    int tid = threadIdx.x;
    const float4* w4 = (const float4*)(w + (size_t)blockIdx.x * 4096);
    float s = 0.f;
#pragma unroll
    for (int i = 0; i < 4; ++i) {
        float4 v = w4[tid + i * 256];
        s += fabsf(v.x) + fabsf(v.y) + fabsf(v.z) + fabsf(v.w);
    }
#pragma unroll
    for (int o = 32; o > 0; o >>= 1) s += __shfl_xor(s, o);
    __shared__ float rb[4];
    if ((tid & 63) == 0) rb[tid >> 6] = s;
    __syncthreads();
    if (tid == 0) partial[blockIdx.x] = rb[0] + rb[1] + rb[2] + rb[3];
}

// ---------------- finalize weight scale ----------------
__global__ __launch_bounds__(256) void k_wscale(const float* __restrict__ partial,
                                                float* __restrict__ wsp) {
    int tid = threadIdx.x;
    float s = 0.f;
#pragma unroll
    for (int i = 0; i < 16; ++i) s += partial[tid + i * 256];
#pragma unroll
    for (int o = 32; o > 0; o >>= 1) s += __shfl_xor(s, o);
    __shared__ float rb[4];
    if ((tid & 63) == 0) rb[tid >> 6] = s;
    __syncthreads();
    if (tid == 0)
        wsp[0] = fmaxf((rb[0] + rb[1] + rb[2] + rb[3]) * (1.0f / 16777216.0f), 1e-5f);
}

// ---------------- ternary weight quant ----------------
__global__ __launch_bounds__(256) void k_wquant(const float* __restrict__ w,
                                                const float* __restrict__ wsp,
                                                unsigned int* __restrict__ wq) {
    int idx = blockIdx.x * 256 + threadIdx.x;   // float4 group index
    float ws = wsp[0];
    float4 v = ((const float4*)w)[idx];
    int a = (int)rintf(v.x / ws); a = max(-1, min(1, a));
    int b = (int)rintf(v.y / ws); b = max(-1, min(1, b));
    int c = (int)rintf(v.z / ws); c = max(-1, min(1, c));
    int d = (int)rintf(v.w / ws); d = max(-1, min(1, d));
    unsigned int p = (unsigned)(a & 255) | ((unsigned)(b & 255) << 8) |
                     ((unsigned)(c & 255) << 16) | ((unsigned)(d & 255) << 24);
    wq[idx] = p;
}

// ---------------- fused LayerNorm + pad + FWHT + int8 absmax quant ----------------
__global__ __launch_bounds__(256) void k_lnfwht(const float* __restrict__ x,
                                                const float* __restrict__ gamma,
                                                const float* __restrict__ beta,
                                                unsigned int* __restrict__ q,
                                                float* __restrict__ ainv) {
    __shared__ float s[PAD_F];
    __shared__ float rb[8];
    int tid = threadIdx.x;
    int t = blockIdx.x;
    const float* xr = x + (size_t)t * IN_F;

    float v[12];
    float sum = 0.f;
#pragma unroll
    for (int i = 0; i < 12; ++i) { v[i] = xr[tid + i * 256]; sum += v[i]; }
#pragma unroll
    for (int o = 32; o > 0; o >>= 1) sum += __shfl_xor(sum, o);
    if ((tid & 63) == 0) rb[tid >> 6] = sum;
    __syncthreads();
    float mu = (rb[0] + rb[1] + rb[2] + rb[3]) * (1.0f / 3072.0f);

    float s2 = 0.f;
#pragma unroll
    for (int i = 0; i < 12; ++i) { float d = v[i] - mu; s2 += d * d; }
#pragma unroll
    for (int o = 32; o > 0; o >>= 1) s2 += __shfl_xor(s2, o);
    if ((tid & 63) == 0) rb[4 + (tid >> 6)] = s2;
    __syncthreads();
    float var = (rb[4] + rb[5] + rb[6] + rb[7]) * (1.0f / 3072.0f);
    float rstd = 1.0f / sqrtf(var + 1e-6f);

#pragma unroll
    for (int i = 0; i < 12; ++i) {
        int idx = tid + i * 256;
        s[idx] = (v[i] - mu) * rstd * gamma[idx] + beta[idx];
    }
#pragma unroll
    for (int i = 0; i < 4; ++i) s[IN_F + tid + i * 256] = 0.f;
    __syncthreads();

    // FWHT, 12 stages
    for (int h = 1; h < PAD_F; h <<= 1) {
#pragma unroll
        for (int jj = 0; jj < 8; ++jj) {
            int j = tid + jj * 256;                       // 0..2047
            int i0 = ((j & ~(h - 1)) << 1) | (j & (h - 1));
            float a = s[i0], b = s[i0 + h];
            s[i0] = a + b;
            s[i0 + h] = a - b;
        }
        __syncthreads();
    }

    // absmax of fwht/64
    float mx = 0.f;
#pragma unroll
    for (int i = 0; i < 16; ++i) mx = fmaxf(mx, fabsf(s[tid + i * 256]));
#pragma unroll
    for (int o = 32; o > 0; o >>= 1) mx = fmaxf(mx, __shfl_xor(mx, o));
    if ((tid & 63) == 0) rb[tid >> 6] = mx;
    __syncthreads();
    float amraw = fmaxf(fmaxf(rb[0], rb[1]), fmaxf(rb[2], rb[3]));
    float amax = fmaxf(amraw * (1.0f / 64.0f), 1e-5f);
    float scale = 127.0f / amax;
    if (tid == 0) ainv[t] = amax * (1.0f / 127.0f);

    unsigned int* qr = q + (size_t)t * (PAD_F / 4);
#pragma unroll
    for (int i = 0; i < 4; ++i) {
        int g = tid + i * 256;                 // int8x4 group
        unsigned int p = 0;
#pragma unroll
        for (int e = 0; e < 4; ++e) {
            float xh = s[4 * g + e] * (1.0f / 64.0f);
            int qi = (int)rintf(xh * scale);
            qi = max(-128, min(127, qi));
            p |= (unsigned)(qi & 255) << (8 * e);
        }
        qr[g] = p;
    }
}

// ---------------- int8 MFMA GEMM, 256x256 tile, BK=128, 2-phase prefetch ----------------
// out[m][n] = (sum_k q[m][k]*t[n][k]) * wsc * ainv[m]
// LDS layout per half-K-tile row: [row][chunk^(row&7)] (XOR swizzle, conflict-free reads).
// global_load_lds writes linearly; swizzle realized by permuting per-lane SOURCE chunk.
#define NT 32   // K tiles of BK=128

__global__ __launch_bounds__(512, 2) void k_gemm(const signed char* __restrict__ Aq,
                                                 const signed char* __restrict__ Wq,
                                                 const float* __restrict__ ainv,
                                                 const float* __restrict__ wsp,
                                                 float* __restrict__ out) {
    __shared__ signed char sA[2][256 * 128];
    __shared__ signed char sB[2][256 * 128];

    int tid = threadIdx.x;
    int lane = tid & 63, wid = tid >> 6;

    // bijective XCD swizzle (nwg=512, 512%8==0): XCD x owns swz in [64x, 64x+64)
    int bid = blockIdx.x;
    int swz = (bid & 7) * 64 + (bid >> 3);
    int bmb = swz & 31;        // 32 row-blocks (M=8192)
    int bnb = swz >> 5;        // 16 col-blocks (N=4096); per XCD: 2 B-panels (2MB, L2-fit)
    size_t bm0 = (size_t)bmb * 256, bn0 = (size_t)bnb * 256;

    int wm = wid >> 2, wn = wid & 3;     // 2M x 4N waves; wave tile 128x64
    int l8 = lane >> 3, l7 = lane & 7;
    int lrow = lane & 15, hi = lane >> 4;

    // staging source: lane l -> row (l>>3) of 8-row group, source chunk (l&7)^(l>>3)
    const signed char* gA = Aq + (bm0 + (size_t)(wid * 32 + l8)) * K_DIM + (size_t)((l7 ^ l8) * 16);
    const signed char* gB = Wq + (bn0 + (size_t)(wid * 32 + l8)) * K_DIM + (size_t)((l7 ^ l8) * 16);

    i32x4 acc[8][4];
#pragma unroll
    for (int m = 0; m < 8; ++m)
#pragma unroll
        for (int n = 0; n < 4; ++n) acc[m][n] = (i32x4){0, 0, 0, 0};

    // fragment read bases (i32x4 units): row*8 + (chunk ^ (row&7))
    int abase = (wm * 128 + lrow) * 8;
    int bbase = (wn * 64 + lrow) * 8;

    auto STAGE = [&](int b, int k0) {
#pragma unroll
        for (int i = 0; i < 4; ++i) {
            gload_lds16(gA + (size_t)k0 + (size_t)i * 8 * K_DIM, &sA[b][(wid * 32 + i * 8) * 128]);
            gload_lds16(gB + (size_t)k0 + (size_t)i * 8 * K_DIM, &sB[b][(wid * 32 + i * 8) * 128]);
        }
    };

    auto COMPUTE = [&](int b) {
        const i32x4* va = (const i32x4*)&sA[b][0];
        const i32x4* vb = (const i32x4*)&sB[b][0];
#pragma unroll
        for (int ks = 0; ks < 2; ++ks) {
            int kx = (ks * 4 + hi) ^ l7;
            i32x4 af[8], bf[4];
#pragma unroll
            for (int m = 0; m < 8; ++m) af[m] = va[abase + m * 128 + kx];
#pragma unroll
            for (int n = 0; n < 4; ++n) bf[n] = vb[bbase + n * 128 + kx];
            __builtin_amdgcn_s_setprio(1);
#pragma unroll
            for (int m = 0; m < 8; ++m)
#pragma unroll
                for (int n = 0; n < 4; ++n)
                    acc[m][n] = __builtin_amdgcn_mfma_i32_16x16x64_i8(af[m], bf[n], acc[m][n], 0, 0, 0);
            __builtin_amdgcn_s_setprio(0);
        }
    };

    STAGE(0, 0);
    __syncthreads();                       // drains vmcnt(0): tile 0 ready

#pragma unroll 1
    for (int t = 0; t < NT - 1; ++t) {
        STAGE((t + 1) & 1, (t + 1) * 128); // prefetch next tile (flies under MFMA)
        COMPUTE(t & 1);
        __syncthreads();                   // drains vmcnt+lgkmcnt: next ready, cur reads done
    }
    COMPUTE((NT - 1) & 1);

    float wsc = wsp[0];
#pragma unroll
    for (int m = 0; m < 8; ++m) {
        size_t row0 = bm0 + wm * 128 + m * 16 + hi * 4;
#pragma unroll
        for (int r = 0; r < 4; ++r) {
            size_t row = row0 + r;
            float sa = wsc * ainv[row];
#pragma unroll
            for (int n = 0; n < 4; ++n) {
                size_t col = bn0 + wn * 64 + n * 16 + lrow;
                out[row * N_OUT + col] = (float)acc[m][n][r] * sa;
            }
        }
    }
}

extern "C" void kernel_launch(void* const* d_in, const int* in_sizes, int n_in,
                              void* d_out, int out_size, void* d_ws, size_t ws_size,
                              hipStream_t stream) {
    const float* x     = (const float*)d_in[0];
    const float* gamma = (const float*)d_in[1];
    const float* beta  = (const float*)d_in[2];
    const float* w     = (const float*)d_in[3];
    float* out = (float*)d_out;
    char* ws = (char*)d_ws;

    signed char* q   = (signed char*)(ws + Q_OFF);
    signed char* wq  = (signed char*)(ws + WQ_OFF);
    float* ainv      = (float*)(ws + AINV_OFF);
    float* partial   = (float*)(ws + PART_OFF);
    float* wsp       = (float*)(ws + WSC_OFF);

    k_wabs<<<dim3(4096), dim3(256), 0, stream>>>(w, partial);
    k_wscale<<<dim3(1), dim3(256), 0, stream>>>(partial, wsp);
    k_wquant<<<dim3(16384), dim3(256), 0, stream>>>(w, wsp, (unsigned int*)wq);
    k_lnfwht<<<dim3(TOKENS), dim3(256), 0, stream>>>(x, gamma, beta, (unsigned int*)q, ainv);
    k_gemm<<<dim3(512), dim3(512), 0, stream>>>(q, wq, ainv, wsp, out);
}

// Round 3
// 244.811 us; speedup vs baseline: 1.0954x; 1.0255x over previous
//
#include <hip/hip_runtime.h>
#include <stdint.h>

// Problem dims
#define TOKENS 8192      // 4*2048
#define IN_F   3072
#define PAD_F  4096
#define N_OUT  4096
#define K_DIM  4096

using i32x4 = __attribute__((ext_vector_type(4))) int;

// -------- workspace layout (bytes) --------
#define Q_OFF    0
#define WQ_OFF   33554432
#define AINV_OFF 50331648
#define PART_OFF 50364416
#define WSC_OFF  50380800

__device__ __forceinline__ void gload_lds16(const void* g, void* l) {
    __builtin_amdgcn_global_load_lds(
        (__attribute__((address_space(1))) void*)(void*)g,
        (__attribute__((address_space(3))) void*)l,
        16, 0, 0);
}

// ---------------- weight absmean: partial sums ----------------
__global__ __launch_bounds__(256) void k_wabs(const float* __restrict__ w,
                                              float* __restrict__ partial) {
    int tid = threadIdx.x;
    const float4* w4 = (const float4*)(w + (size_t)blockIdx.x * 4096);
    float s = 0.f;
#pragma unroll
    for (int i = 0; i < 4; ++i) {
        float4 v = w4[tid + i * 256];
        s += fabsf(v.x) + fabsf(v.y) + fabsf(v.z) + fabsf(v.w);
    }
#pragma unroll
    for (int o = 32; o > 0; o >>= 1) s += __shfl_xor(s, o);
    __shared__ float rb[4];
    if ((tid & 63) == 0) rb[tid >> 6] = s;
    __syncthreads();
    if (tid == 0) partial[blockIdx.x] = rb[0] + rb[1] + rb[2] + rb[3];
}

// ---------------- finalize weight scale ----------------
__global__ __launch_bounds__(256) void k_wscale(const float* __restrict__ partial,
                                                float* __restrict__ wsp) {
    int tid = threadIdx.x;
    float s = 0.f;
#pragma unroll
    for (int i = 0; i < 16; ++i) s += partial[tid + i * 256];
#pragma unroll
    for (int o = 32; o > 0; o >>= 1) s += __shfl_xor(s, o);
    __shared__ float rb[4];
    if ((tid & 63) == 0) rb[tid >> 6] = s;
    __syncthreads();
    if (tid == 0)
        wsp[0] = fmaxf((rb[0] + rb[1] + rb[2] + rb[3]) * (1.0f / 16777216.0f), 1e-5f);
}

// ---------------- ternary weight quant ----------------
__global__ __launch_bounds__(256) void k_wquant(const float* __restrict__ w,
                                                const float* __restrict__ wsp,
                                                unsigned int* __restrict__ wq) {
    int idx = blockIdx.x * 256 + threadIdx.x;   // float4 group index
    float ws = wsp[0];
    float4 v = ((const float4*)w)[idx];
    int a = (int)rintf(v.x / ws); a = max(-1, min(1, a));
    int b = (int)rintf(v.y / ws); b = max(-1, min(1, b));
    int c = (int)rintf(v.z / ws); c = max(-1, min(1, c));
    int d = (int)rintf(v.w / ws); d = max(-1, min(1, d));
    unsigned int p = (unsigned)(a & 255) | ((unsigned)(b & 255) << 8) |
                     ((unsigned)(c & 255) << 16) | ((unsigned)(d & 255) << 24);
    wq[idx] = p;
}

// ---------------- fused LayerNorm + pad + FWHT + int8 absmax quant ----------------
// Register/shfl FWHT: slot j = tid + 256*i. Bits 8-11 of j = i (in-register,
// h=256..2048), bits 0-5 = lane (shfl_xor, h=1..32), bits 6-7 = wave (LDS, h=64,128).
__global__ __launch_bounds__(256) void k_lnfwht(const float* __restrict__ x,
                                                const float* __restrict__ gamma,
                                                const float* __restrict__ beta,
                                                signed char* __restrict__ q,
                                                float* __restrict__ ainv) {
    __shared__ float s[PAD_F];
    __shared__ float rb[8];
    int tid = threadIdx.x;
    int lane = tid & 63;
    int t = blockIdx.x;
    const float* xr = x + (size_t)t * IN_F;

    float v[16];
    float sum = 0.f;
#pragma unroll
    for (int i = 0; i < 12; ++i) { v[i] = xr[tid + i * 256]; sum += v[i]; }
    v[12] = v[13] = v[14] = v[15] = 0.f;
#pragma unroll
    for (int o = 32; o > 0; o >>= 1) sum += __shfl_xor(sum, o);
    if ((tid & 63) == 0) rb[tid >> 6] = sum;
    __syncthreads();
    float mu = (rb[0] + rb[1] + rb[2] + rb[3]) * (1.0f / 3072.0f);

    float s2 = 0.f;
#pragma unroll
    for (int i = 0; i < 12; ++i) { float d = v[i] - mu; s2 += d * d; }
#pragma unroll
    for (int o = 32; o > 0; o >>= 1) s2 += __shfl_xor(s2, o);
    if ((tid & 63) == 0) rb[4 + (tid >> 6)] = s2;
    __syncthreads();
    float var = (rb[4] + rb[5] + rb[6] + rb[7]) * (1.0f / 3072.0f);
    float rstd = 1.0f / sqrtf(var + 1e-6f);

#pragma unroll
    for (int i = 0; i < 12; ++i)
        v[i] = (v[i] - mu) * rstd * gamma[tid + i * 256] + beta[tid + i * 256];

    // FWHT group 1: bits 8-11 (register index i), h = 256,512,1024,2048
#pragma unroll
    for (int b = 1; b < 16; b <<= 1) {
#pragma unroll
        for (int i = 0; i < 16; ++i) {
            if (!(i & b)) {
                float a0 = v[i], b0 = v[i | b];
                v[i] = a0 + b0;
                v[i | b] = a0 - b0;
            }
        }
    }
    // group 2: bits 0-5 (lane), h = 1..32 via shfl_xor
#pragma unroll
    for (int m = 1; m <= 32; m <<= 1) {
#pragma unroll
        for (int i = 0; i < 16; ++i) {
            float p = __shfl_xor(v[i], m);
            v[i] = (lane & m) ? (p - v[i]) : (v[i] + p);
        }
    }
    // group 3: bits 6-7 (wave id), h = 64,128 via LDS
#pragma unroll
    for (int m = 64; m <= 128; m <<= 1) {
        __syncthreads();
#pragma unroll
        for (int i = 0; i < 16; ++i) s[tid + i * 256] = v[i];
        __syncthreads();
#pragma unroll
        for (int i = 0; i < 16; ++i) {
            float p = s[(tid ^ m) + i * 256];
            v[i] = (tid & m) ? (p - v[i]) : (v[i] + p);
        }
    }

    // absmax of fwht/64
    float mx = 0.f;
#pragma unroll
    for (int i = 0; i < 16; ++i) mx = fmaxf(mx, fabsf(v[i]));
#pragma unroll
    for (int o = 32; o > 0; o >>= 1) mx = fmaxf(mx, __shfl_xor(mx, o));
    __syncthreads();
    if ((tid & 63) == 0) rb[tid >> 6] = mx;
    __syncthreads();
    float amraw = fmaxf(fmaxf(rb[0], rb[1]), fmaxf(rb[2], rb[3]));
    float amax = fmaxf(amraw * (1.0f / 64.0f), 1e-5f);
    float scale = 127.0f / amax;
    if (tid == 0) ainv[t] = amax * (1.0f / 127.0f);

    signed char* qr = q + (size_t)t * PAD_F;
#pragma unroll
    for (int i = 0; i < 16; ++i) {
        int qi = (int)rintf(v[i] * (1.0f / 64.0f) * scale);
        qi = max(-128, min(127, qi));
        qr[tid + i * 256] = (signed char)qi;
    }
}

// ---------------- int8 MFMA GEMM, 256x256 tile, BK=64, depth-3 counted-vmcnt pipeline ----------------
// out[m][n] = (sum_k q[m][k]*t[n][k]) * wsc * ainv[m]
// LDS row = 64B = 4 chunks of 16B; chunk stored at position chunk ^ ((row>>1)&3)
// (conflict-free ds_read_b128; realized via pre-swizzled global source, rule #21).
#define BK 64
#define NT (K_DIM / BK)   // 64

__global__ __launch_bounds__(512, 2) void k_gemm(const signed char* __restrict__ Aq,
                                                 const signed char* __restrict__ Wq,
                                                 const float* __restrict__ ainv,
                                                 const float* __restrict__ wsp,
                                                 float* __restrict__ out) {
    __shared__ signed char sA[4][256 * BK];   // 4 x 16 KB
    __shared__ signed char sB[4][256 * BK];   // 4 x 16 KB

    int tid = threadIdx.x;
    int lane = tid & 63, wid = tid >> 6;

    // XCD partition: XCD x owns bm in {4x..4x+3} (A 4MB L2-resident), sweeps bn
    // bm-inner-4 so consecutive blocks share the B panel.
    int bid = blockIdx.x;
    int xcd = bid & 7, li = bid >> 3;       // li in 0..63
    int bmb = xcd * 4 + (li & 3);
    int bnb = li >> 2;                       // 0..15
    size_t bm0 = (size_t)bmb * 256, bn0 = (size_t)bnb * 256;

    int wm = wid >> 2, wn = wid & 3;         // 2M x 4N waves; wave tile 128x64
    int lrow = lane & 15, hi = lane >> 4;

    // staging: lane -> row lane>>2 (16 rows/gload), source chunk (lane&3)^((lane>>3)&3)
    int srow = lane >> 2;
    int schunk = (lane & 3) ^ ((lane >> 3) & 3);
    const signed char* gA = Aq + (bm0 + (size_t)(wid * 32 + srow)) * K_DIM + schunk * 16;
    const signed char* gB = Wq + (bn0 + (size_t)(wid * 32 + srow)) * K_DIM + schunk * 16;

    i32x4 acc[8][4];
#pragma unroll
    for (int m = 0; m < 8; ++m)
#pragma unroll
        for (int n = 0; n < 4; ++n) acc[m][n] = (i32x4){0, 0, 0, 0};

    // fragment read: row*4 + (hi ^ ((row>>1)&3)); row = base16 + (lane&15)
    int kx = hi ^ ((lane >> 1) & 3);
    int abase = (wm * 128 + lrow) * 4 + kx;
    int bbase = (wn * 64 + lrow) * 4 + kx;

    auto STAGE = [&](int b, int t) {
        size_t k0 = (size_t)t * BK;
        gload_lds16(gA + k0, &sA[b][(wid * 32) * BK]);
        gload_lds16(gA + k0 + (size_t)16 * K_DIM, &sA[b][(wid * 32 + 16) * BK]);
        gload_lds16(gB + k0, &sB[b][(wid * 32) * BK]);
        gload_lds16(gB + k0 + (size_t)16 * K_DIM, &sB[b][(wid * 32 + 16) * BK]);
    };

    auto COMPUTE = [&](int b) {
        const i32x4* va = (const i32x4*)&sA[b][0];
        const i32x4* vb = (const i32x4*)&sB[b][0];
        i32x4 af[8], bf[4];
#pragma unroll
        for (int m = 0; m < 8; ++m) af[m] = va[abase + m * 64];
#pragma unroll
        for (int n = 0; n < 4; ++n) bf[n] = vb[bbase + n * 64];
        __builtin_amdgcn_s_setprio(1);
#pragma unroll
        for (int m = 0; m < 8; ++m)
#pragma unroll
            for (int n = 0; n < 4; ++n)
                acc[m][n] = __builtin_amdgcn_mfma_i32_16x16x64_i8(af[m], bf[n], acc[m][n], 0, 0, 0);
        __builtin_amdgcn_s_setprio(0);
    };

    STAGE(0, 0);
    STAGE(1, 1);
    STAGE(2, 2);                 // 12 loads in flight

#pragma unroll 1
    for (int t = 0; t < NT - 3; ++t) {
        STAGE((t + 3) & 3, t + 3);                         // 16 in flight
        asm volatile("s_waitcnt vmcnt(12)" ::: "memory");  // STAGE(t) landed (own wave)
        __builtin_amdgcn_s_barrier();                      // all waves' STAGE(t) landed
        __builtin_amdgcn_sched_barrier(0);
        COMPUTE(t & 3);
        __builtin_amdgcn_sched_barrier(0);
        __builtin_amdgcn_s_barrier();                      // reads of buf[t&3] done (freed for t+4)
    }
    asm volatile("s_waitcnt vmcnt(8)" ::: "memory");
    __builtin_amdgcn_s_barrier();
    __builtin_amdgcn_sched_barrier(0);
    COMPUTE((NT - 3) & 3);
    asm volatile("s_waitcnt vmcnt(4)" ::: "memory");
    __builtin_amdgcn_s_barrier();
    __builtin_amdgcn_sched_barrier(0);
    COMPUTE((NT - 2) & 3);
    asm volatile("s_waitcnt vmcnt(0)" ::: "memory");
    __builtin_amdgcn_s_barrier();
    __builtin_amdgcn_sched_barrier(0);
    COMPUTE((NT - 1) & 3);

    float wsc = wsp[0];
#pragma unroll
    for (int m = 0; m < 8; ++m) {
        size_t row0 = bm0 + wm * 128 + m * 16 + hi * 4;
#pragma unroll
        for (int r = 0; r < 4; ++r) {
            size_t row = row0 + r;
            float sa = wsc * ainv[row];
#pragma unroll
            for (int n = 0; n < 4; ++n) {
                size_t col = bn0 + wn * 64 + n * 16 + lrow;
                out[row * N_OUT + col] = (float)acc[m][n][r] * sa;
            }
        }
    }
}

extern "C" void kernel_launch(void* const* d_in, const int* in_sizes, int n_in,
                              void* d_out, int out_size, void* d_ws, size_t ws_size,
                              hipStream_t stream) {
    const float* x     = (const float*)d_in[0];
    const float* gamma = (const float*)d_in[1];
    const float* beta  = (const float*)d_in[2];
    const float* w     = (const float*)d_in[3];
    float* out = (float*)d_out;
    char* ws = (char*)d_ws;

    signed char* q   = (signed char*)(ws + Q_OFF);
    signed char* wq  = (signed char*)(ws + WQ_OFF);
    float* ainv      = (float*)(ws + AINV_OFF);
    float* partial   = (float*)(ws + PART_OFF);
    float* wsp       = (float*)(ws + WSC_OFF);

    k_wabs<<<dim3(4096), dim3(256), 0, stream>>>(w, partial);
    k_wscale<<<dim3(1), dim3(256), 0, stream>>>(partial, wsp);
    k_wquant<<<dim3(16384), dim3(256), 0, stream>>>(w, wsp, (unsigned int*)wq);
    k_lnfwht<<<dim3(TOKENS), dim3(256), 0, stream>>>(x, gamma, beta, q, ainv);
    k_gemm<<<dim3(512), dim3(512), 0, stream>>>(q, wq, ainv, wsp, out);
}

// Round 4
// 231.152 us; speedup vs baseline: 1.1601x; 1.0591x over previous
//
#include <hip/hip_runtime.h>
#include <stdint.h>

// Problem dims
#define TOKENS 8192      // 4*2048
#define IN_F   3072
#define PAD_F  4096
#define N_OUT  4096
#define K_DIM  4096

using i32x4  = __attribute__((ext_vector_type(4))) int;
using i32x16 = __attribute__((ext_vector_type(16))) int;

// -------- workspace layout (bytes) --------
#define Q_OFF    0
#define WQ_OFF   33554432
#define AINV_OFF 50331648
#define PART_OFF 50364416
#define WSC_OFF  50380800

__device__ __forceinline__ void gload_lds16(const void* g, void* l) {
    __builtin_amdgcn_global_load_lds(
        (__attribute__((address_space(1))) void*)(void*)g,
        (__attribute__((address_space(3))) void*)l,
        16, 0, 0);
}

// ---------------- weight absmean: partial sums ----------------
__global__ __launch_bounds__(256) void k_wabs(const float* __restrict__ w,
                                              float* __restrict__ partial) {
    int tid = threadIdx.x;
    const float4* w4 = (const float4*)(w + (size_t)blockIdx.x * 4096);
    float s = 0.f;
#pragma unroll
    for (int i = 0; i < 4; ++i) {
        float4 v = w4[tid + i * 256];
        s += fabsf(v.x) + fabsf(v.y) + fabsf(v.z) + fabsf(v.w);
    }
#pragma unroll
    for (int o = 32; o > 0; o >>= 1) s += __shfl_xor(s, o);
    __shared__ float rb[4];
    if ((tid & 63) == 0) rb[tid >> 6] = s;
    __syncthreads();
    if (tid == 0) partial[blockIdx.x] = rb[0] + rb[1] + rb[2] + rb[3];
}

// ---------------- finalize weight scale ----------------
__global__ __launch_bounds__(256) void k_wscale(const float* __restrict__ partial,
                                                float* __restrict__ wsp) {
    int tid = threadIdx.x;
    float s = 0.f;
#pragma unroll
    for (int i = 0; i < 16; ++i) s += partial[tid + i * 256];
#pragma unroll
    for (int o = 32; o > 0; o >>= 1) s += __shfl_xor(s, o);
    __shared__ float rb[4];
    if ((tid & 63) == 0) rb[tid >> 6] = s;
    __syncthreads();
    if (tid == 0)
        wsp[0] = fmaxf((rb[0] + rb[1] + rb[2] + rb[3]) * (1.0f / 16777216.0f), 1e-5f);
}

// ---------------- ternary weight quant ----------------
__global__ __launch_bounds__(256) void k_wquant(const float* __restrict__ w,
                                                const float* __restrict__ wsp,
                                                unsigned int* __restrict__ wq) {
    int idx = blockIdx.x * 256 + threadIdx.x;   // float4 group index
    float ws = wsp[0];
    float4 v = ((const float4*)w)[idx];
    int a = (int)rintf(v.x / ws); a = max(-1, min(1, a));
    int b = (int)rintf(v.y / ws); b = max(-1, min(1, b));
    int c = (int)rintf(v.z / ws); c = max(-1, min(1, c));
    int d = (int)rintf(v.w / ws); d = max(-1, min(1, d));
    unsigned int p = (unsigned)(a & 255) | ((unsigned)(b & 255) << 8) |
                     ((unsigned)(c & 255) << 16) | ((unsigned)(d & 255) << 24);
    wq[idx] = p;
}

// ---------------- fused LayerNorm + pad + FWHT + int8 absmax quant ----------------
__global__ __launch_bounds__(256) void k_lnfwht(const float* __restrict__ x,
                                                const float* __restrict__ gamma,
                                                const float* __restrict__ beta,
                                                signed char* __restrict__ q,
                                                float* __restrict__ ainv) {
    __shared__ float s[PAD_F];
    __shared__ float rb[8];
    int tid = threadIdx.x;
    int lane = tid & 63;
    int t = blockIdx.x;
    const float* xr = x + (size_t)t * IN_F;

    float v[16];
    float sum = 0.f;
#pragma unroll
    for (int i = 0; i < 12; ++i) { v[i] = xr[tid + i * 256]; sum += v[i]; }
    v[12] = v[13] = v[14] = v[15] = 0.f;
#pragma unroll
    for (int o = 32; o > 0; o >>= 1) sum += __shfl_xor(sum, o);
    if ((tid & 63) == 0) rb[tid >> 6] = sum;
    __syncthreads();
    float mu = (rb[0] + rb[1] + rb[2] + rb[3]) * (1.0f / 3072.0f);

    float s2 = 0.f;
#pragma unroll
    for (int i = 0; i < 12; ++i) { float d = v[i] - mu; s2 += d * d; }
#pragma unroll
    for (int o = 32; o > 0; o >>= 1) s2 += __shfl_xor(s2, o);
    if ((tid & 63) == 0) rb[4 + (tid >> 6)] = s2;
    __syncthreads();
    float var = (rb[4] + rb[5] + rb[6] + rb[7]) * (1.0f / 3072.0f);
    float rstd = 1.0f / sqrtf(var + 1e-6f);

#pragma unroll
    for (int i = 0; i < 12; ++i)
        v[i] = (v[i] - mu) * rstd * gamma[tid + i * 256] + beta[tid + i * 256];

    // FWHT group 1: bits 8-11 (register index i)
#pragma unroll
    for (int b = 1; b < 16; b <<= 1) {
#pragma unroll
        for (int i = 0; i < 16; ++i) {
            if (!(i & b)) {
                float a0 = v[i], b0 = v[i | b];
                v[i] = a0 + b0;
                v[i | b] = a0 - b0;
            }
        }
    }
    // group 2: bits 0-5 (lane) via shfl_xor
#pragma unroll
    for (int m = 1; m <= 32; m <<= 1) {
#pragma unroll
        for (int i = 0; i < 16; ++i) {
            float p = __shfl_xor(v[i], m);
            v[i] = (lane & m) ? (p - v[i]) : (v[i] + p);
        }
    }
    // group 3: bits 6-7 (wave id) via LDS
#pragma unroll
    for (int m = 64; m <= 128; m <<= 1) {
        __syncthreads();
#pragma unroll
        for (int i = 0; i < 16; ++i) s[tid + i * 256] = v[i];
        __syncthreads();
#pragma unroll
        for (int i = 0; i < 16; ++i) {
            float p = s[(tid ^ m) + i * 256];
            v[i] = (tid & m) ? (p - v[i]) : (v[i] + p);
        }
    }

    // absmax of fwht/64
    float mx = 0.f;
#pragma unroll
    for (int i = 0; i < 16; ++i) mx = fmaxf(mx, fabsf(v[i]));
#pragma unroll
    for (int o = 32; o > 0; o >>= 1) mx = fmaxf(mx, __shfl_xor(mx, o));
    __syncthreads();
    if ((tid & 63) == 0) rb[tid >> 6] = mx;
    __syncthreads();
    float amraw = fmaxf(fmaxf(rb[0], rb[1]), fmaxf(rb[2], rb[3]));
    float amax = fmaxf(amraw * (1.0f / 64.0f), 1e-5f);
    float scale = 127.0f / amax;
    if (tid == 0) ainv[t] = amax * (1.0f / 127.0f);

    signed char* qr = q + (size_t)t * PAD_F;
#pragma unroll
    for (int i = 0; i < 16; ++i) {
        int qi = (int)rintf(v[i] * (1.0f / 64.0f) * scale);
        qi = max(-128, min(127, qi));
        qr[tid + i * 256] = (signed char)qi;
    }
}

// ---------------- int8 MFMA GEMM, 256x256 tile, BK=64, 4-buffer ring ----------------
// out[m][n] = (sum_k q[m][k]*t[n][k]) * wsc * ainv[m]
// mfma_i32_32x32x32_i8; register-fragment double-buffer: ds_read(t+1) overlaps MFMA(t).
// LDS row = 64B = 4 chunks of 16B at position chunk ^ ((row>>1)&3) (conflict-free;
// realized via pre-swizzled global source, rule #21).
#define BK 64
#define NT (K_DIM / BK)   // 64

__global__ __launch_bounds__(512, 2) void k_gemm(const signed char* __restrict__ Aq,
                                                 const signed char* __restrict__ Wq,
                                                 const float* __restrict__ ainv,
                                                 const float* __restrict__ wsp,
                                                 float* __restrict__ out) {
    __shared__ signed char sA[4][256 * BK];   // 4 x 16 KB
    __shared__ signed char sB[4][256 * BK];

    int tid = threadIdx.x;
    int lane = tid & 63, wid = tid >> 6;

    // XCD partition: XCD x owns bm in {4x..4x+3} (A L2-resident), sweeps bn.
    int bid = blockIdx.x;
    int xcd = bid & 7, li = bid >> 3;
    int bmb = xcd * 4 + (li & 3);
    int bnb = li >> 2;
    size_t bm0 = (size_t)bmb * 256, bn0 = (size_t)bnb * 256;

    int wm = wid >> 2, wn = wid & 3;          // 2M x 4N waves; wave tile 128x64

    // staging: lane -> row lane>>2 (16 rows/gload), source chunk (lane&3)^((lane>>3)&3)
    int srow = lane >> 2;
    int schunk = (lane & 3) ^ ((lane >> 3) & 3);
    const signed char* gA = Aq + (bm0 + (size_t)(wid * 32 + srow)) * K_DIM + schunk * 16;
    const signed char* gB = Wq + (bn0 + (size_t)(wid * 32 + srow)) * K_DIM + schunk * 16;

    // 32x32x32 fragment addressing: lane -> row r32 = lane&31, kseg = lane>>5 (16B)
    int r32 = lane & 31, ks32 = lane >> 5;
    int kq = ks32 ^ ((r32 >> 1) & 3);          // swizzled chunk base
    int abase = (wm * 128 + r32) * 4;
    int bbase = (wn * 64 + r32) * 4;

    i32x16 acc[4][2];
#pragma unroll
    for (int mf = 0; mf < 4; ++mf)
#pragma unroll
        for (int nf = 0; nf < 2; ++nf) acc[mf][nf] = (i32x16)(0);

    i32x4 afA[2][4], bfA[2][2], afB[2][4], bfB[2][2];

    auto STAGE = [&](int b, int t) {
        size_t k0 = (size_t)t * BK;
        gload_lds16(gA + k0, &sA[b][(wid * 32) * BK]);
        gload_lds16(gA + k0 + (size_t)16 * K_DIM, &sA[b][(wid * 32 + 16) * BK]);
        gload_lds16(gB + k0, &sB[b][(wid * 32) * BK]);
        gload_lds16(gB + k0 + (size_t)16 * K_DIM, &sB[b][(wid * 32 + 16) * BK]);
    };

#define LOADF(B, AF, BF) do {                                           \
    const i32x4* va = (const i32x4*)&sA[B][0];                          \
    const i32x4* vb = (const i32x4*)&sB[B][0];                          \
    _Pragma("unroll")                                                   \
    for (int ks = 0; ks < 2; ++ks) {                                    \
        int kx = (ks << 1) ^ kq;                                        \
        _Pragma("unroll")                                               \
        for (int mf = 0; mf < 4; ++mf) AF[ks][mf] = va[abase + mf * 128 + kx]; \
        _Pragma("unroll")                                               \
        for (int nf = 0; nf < 2; ++nf) BF[ks][nf] = vb[bbase + nf * 128 + kx]; \
    }                                                                   \
} while (0)

#define COMPUTE(AF, BF) do {                                            \
    __builtin_amdgcn_s_setprio(1);                                      \
    _Pragma("unroll")                                                   \
    for (int ks = 0; ks < 2; ++ks)                                      \
        _Pragma("unroll")                                               \
        for (int mf = 0; mf < 4; ++mf)                                  \
            _Pragma("unroll")                                           \
            for (int nf = 0; nf < 2; ++nf)                              \
                acc[mf][nf] = __builtin_amdgcn_mfma_i32_32x32x32_i8(    \
                    AF[ks][mf], BF[ks][nf], acc[mf][nf], 0, 0, 0);      \
    __builtin_amdgcn_s_setprio(0);                                      \
} while (0)

#define BODY(T, AFC, BFC, AFN, BFN) do {                                \
    STAGE((T + 3) & 3, T + 3);                                          \
    asm volatile("s_waitcnt vmcnt(8)" ::: "memory");                    \
    __builtin_amdgcn_sched_barrier(0);                                  \
    __builtin_amdgcn_s_barrier();                                       \
    __builtin_amdgcn_sched_barrier(0);                                  \
    LOADF((T + 1) & 3, AFN, BFN);                                       \
    COMPUTE(AFC, BFC);                                                  \
    asm volatile("s_waitcnt lgkmcnt(0)" ::: "memory");                  \
    __builtin_amdgcn_sched_barrier(0);                                  \
} while (0)

    // prologue: 3 tiles in flight, tile 0 landed, frags(0) -> A set
    STAGE(0, 0);
    STAGE(1, 1);
    STAGE(2, 2);
    asm volatile("s_waitcnt vmcnt(8)" ::: "memory");
    __builtin_amdgcn_sched_barrier(0);
    __builtin_amdgcn_s_barrier();
    __builtin_amdgcn_sched_barrier(0);
    LOADF(0, afA, bfA);
    asm volatile("s_waitcnt lgkmcnt(0)" ::: "memory");
    __builtin_amdgcn_sched_barrier(0);

#pragma unroll 1
    for (int t = 0; t < NT - 4; t += 2) {
        BODY(t, afA, bfA, afB, bfB);
        BODY(t + 1, afB, bfB, afA, bfA);
    }
    // t = NT-4 = 60: stages tile 63, computes f60
    BODY(NT - 4, afA, bfA, afB, bfB);
    // t = 61
    asm volatile("s_waitcnt vmcnt(4)" ::: "memory");
    __builtin_amdgcn_sched_barrier(0);
    __builtin_amdgcn_s_barrier();
    __builtin_amdgcn_sched_barrier(0);
    LOADF(2, afA, bfA);
    COMPUTE(afB, bfB);
    asm volatile("s_waitcnt lgkmcnt(0)" ::: "memory");
    __builtin_amdgcn_sched_barrier(0);
    // t = 62
    asm volatile("s_waitcnt vmcnt(0)" ::: "memory");
    __builtin_amdgcn_sched_barrier(0);
    __builtin_amdgcn_s_barrier();
    __builtin_amdgcn_sched_barrier(0);
    LOADF(3, afB, bfB);
    COMPUTE(afA, bfA);
    asm volatile("s_waitcnt lgkmcnt(0)" ::: "memory");
    __builtin_amdgcn_sched_barrier(0);
    // t = 63
    COMPUTE(afB, bfB);

    // epilogue: 32x32 C/D layout: col = lane&31, row = (reg&3) + 8*(reg>>2) + 4*(lane>>5)
    float wsc = wsp[0];
    int c31 = lane & 31, hi2 = lane >> 5;
#pragma unroll
    for (int mf = 0; mf < 4; ++mf) {
        size_t rowb = bm0 + wm * 128 + mf * 32 + 4 * hi2;
#pragma unroll
        for (int reg = 0; reg < 16; ++reg) {
            size_t row = rowb + (reg & 3) + 8 * (reg >> 2);
            float sa = wsc * ainv[row];
#pragma unroll
            for (int nf = 0; nf < 2; ++nf) {
                size_t col = bn0 + wn * 64 + nf * 32 + c31;
                out[row * N_OUT + col] = (float)acc[mf][nf][reg] * sa;
            }
        }
    }
#undef LOADF
#undef COMPUTE
#undef BODY
}

extern "C" void kernel_launch(void* const* d_in, const int* in_sizes, int n_in,
                              void* d_out, int out_size, void* d_ws, size_t ws_size,
                              hipStream_t stream) {
    const float* x     = (const float*)d_in[0];
    const float* gamma = (const float*)d_in[1];
    const float* beta  = (const float*)d_in[2];
    const float* w     = (const float*)d_in[3];
    float* out = (float*)d_out;
    char* ws = (char*)d_ws;

    signed char* q   = (signed char*)(ws + Q_OFF);
    signed char* wq  = (signed char*)(ws + WQ_OFF);
    float* ainv      = (float*)(ws + AINV_OFF);
    float* partial   = (float*)(ws + PART_OFF);
    float* wsp       = (float*)(ws + WSC_OFF);

    k_wabs<<<dim3(4096), dim3(256), 0, stream>>>(w, partial);
    k_wscale<<<dim3(1), dim3(256), 0, stream>>>(partial, wsp);
    k_wquant<<<dim3(16384), dim3(256), 0, stream>>>(w, wsp, (unsigned int*)wq);
    k_lnfwht<<<dim3(TOKENS), dim3(256), 0, stream>>>(x, gamma, beta, q, ainv);
    k_gemm<<<dim3(512), dim3(512), 0, stream>>>(q, wq, ainv, wsp, out);
}